// Round 1
// 966.121 us; speedup vs baseline: 1.2401x; 1.2401x over previous
//
#include <hip/hip_runtime.h>
#include <hip/hip_bf16.h>

typedef unsigned short u16;
typedef __attribute__((ext_vector_type(8))) short bfrag;   // 8 bf16 = 4 VGPR
typedef __attribute__((ext_vector_type(4))) float f32x4;

#define B_ 4
#define C_ 128
#define T_ 1000
#define F_ 65
#define H_ 4
#define E_ 8
#define DH_ 32
#define TP_ 199
#define TC_ 398
#define DQK 520      // E*F
#define DQKP 544     // padded K-dim for MFMA (17 chunks of 32)
#define DV 2080      // DH*F
#define SP_ 416      // padded s (26 tiles of 16, 13 chunks of 32)
#define QROWS 1008   // padded T rows (63 tiles of 16)
#define EPS 1e-5f

__device__ __forceinline__ float bf2f(u16 u) {
    union { float f; unsigned int i; } v; v.i = ((unsigned int)u) << 16; return v.f;
}
__device__ __forceinline__ u16 f2bf(float f) {
    union { float f; unsigned int i; } v; v.f = f;
    unsigned int x = v.i;
    return (u16)((x + 0x7FFFu + ((x >> 16) & 1u)) >> 16);
}

__device__ __forceinline__ float ldx(const float* p, int i) { return p[i]; }
__device__ __forceinline__ float ldx(const u16* p, int i) { return bf2f(p[i]); }

__device__ __forceinline__ float wred_sum(float v) {
#pragma unroll
    for (int o = 32; o > 0; o >>= 1) v += __shfl_down(v, o, 64);
    return __shfl(v, 0, 64);
}

// ---------------- 1. avg-pool along T + concat(+pos, -neg) ----------------
__global__ __launch_bounds__(256)
void pool_kernel(const float* __restrict__ pos, const float* __restrict__ neg,
                 u16* __restrict__ cond) {
    int idx = blockIdx.x * 256 + threadIdx.x;
    const int N = B_ * C_ * TC_ * F_;
    if (idx >= N) return;
    int f  = idx % F_;
    int tc = (idx / F_) % TC_;
    int c  = (idx / (F_ * TC_)) % C_;
    int b  = idx / (F_ * TC_ * C_);
    const float* src; float sign; int t0;
    if (tc < TP_) { src = pos; sign =  1.f; t0 = tc * 5; }
    else          { src = neg; sign = -1.f; t0 = (tc - TP_) * 5; }
    int base = ((b * C_ + c) * T_ + t0) * F_ + f;
    float s = 0.f;
#pragma unroll
    for (int k = 0; k < 10; k++) s += src[base + k * F_];
    cond[idx] = f2bf(s * (sign * 0.1f));
}

// ---------------- 2. Q/K branch: conv1x1 + PReLU + LN(E,F) ----------------
// block per (b,t); thread = (row = h*8+e, oct); f = oct + 8j
// writes rows of length `ldout` (Q: 520, K: 544-padded), `rowsper` rows per (h,b)
template <typename XT>
__global__ __launch_bounds__(256)
void qk_branch_kernel(const XT* __restrict__ x, int Tx, int rowsper, int ldout,
                      const float* __restrict__ W, const float* __restrict__ bias,
                      const float* __restrict__ alpha,
                      const float* __restrict__ g, const float* __restrict__ bet,
                      u16* __restrict__ out) {
    __shared__ float xs[C_ * F_ + 8];
    int b = blockIdx.x / Tx, t = blockIdx.x % Tx;
    int tid = threadIdx.x;
    int xbase = (b * C_) * Tx * F_ + t * F_;
    for (int i = tid; i < C_ * F_; i += 256) {
        int c = i / F_, f = i % F_;
        xs[i] = ldx(x, xbase + c * Tx * F_ + f);
    }
    if (tid < 8) xs[C_ * F_ + tid] = 0.f;
    __syncthreads();

    int row = tid >> 3;      // h*8 + e
    int oct = tid & 7;
    int h = row >> 3;
    float acc[9];
    float bb = bias[row];
#pragma unroll
    for (int j = 0; j < 9; j++) acc[j] = bb;
    for (int c = 0; c < C_; c++) {
        float w = W[row * C_ + c];
        const float* xr = &xs[c * F_ + oct];
#pragma unroll
        for (int j = 0; j < 9; j++) acc[j] = fmaf(w, xr[8 * j], acc[j]);
    }
    float a = alpha[h];
    float sum = 0.f, ss = 0.f;
#pragma unroll
    for (int j = 0; j < 9; j++) {
        int f = oct + 8 * j;
        if (f < F_) {
            float v = acc[j];
            v = (v >= 0.f) ? v : a * v;
            acc[j] = v;
            sum += v; ss += v * v;
        }
    }
    sum = wred_sum(sum); ss = wred_sum(ss);
    float mu = sum * (1.f / 520.f);
    float var = ss * (1.f / 520.f) - mu * mu;
    float rs = rsqrtf(var + EPS);
    size_t obase = (size_t)((h * B_ + b) * rowsper + t) * ldout + (row & 7) * F_;
#pragma unroll
    for (int j = 0; j < 9; j++) {
        int f = oct + 8 * j;
        if (f < F_) {
            float gv = g[row * F_ + f];
            float bv = bet[row * F_ + f];
            out[obase + f] = f2bf((acc[j] - mu) * rs * gv + bv);
        }
    }
}

// ---------------- 3. V branch: conv1x1(32 out/head) + PReLU + LN(Dh,F) ----
__global__ __launch_bounds__(256)
void v_branch_kernel(const u16* __restrict__ x,
                     const float* __restrict__ W, const float* __restrict__ bias,
                     const float* __restrict__ alpha,
                     const float* __restrict__ g, const float* __restrict__ bet,
                     u16* __restrict__ out) {
    __shared__ float xs[C_ * F_ + 1];
    int b = blockIdx.x / TC_, t = blockIdx.x % TC_;
    int tid = threadIdx.x;
    int xbase = (b * C_) * TC_ * F_ + t * F_;
    for (int i = tid; i < C_ * F_; i += 256) {
        int c = i / F_, f = i % F_;
        xs[i] = bf2f(x[xbase + c * TC_ * F_ + f]);
    }
    if (tid == 0) xs[C_ * F_] = 0.f;
    __syncthreads();

    int row = tid >> 1;     // h*32 + dh
    int half = tid & 1;
    int h = row >> 5;
    int f0 = half ? 33 : 0;
    float acc[33];
    float bb = bias[row];
#pragma unroll
    for (int j = 0; j < 33; j++) acc[j] = bb;
    for (int c = 0; c < C_; c++) {
        float w = W[row * C_ + c];
        const float* xr = &xs[c * F_ + f0];
#pragma unroll
        for (int j = 0; j < 33; j++) acc[j] = fmaf(w, xr[j], acc[j]);
    }
    float a = alpha[h];
    float sum = 0.f, ss = 0.f;
#pragma unroll
    for (int j = 0; j < 33; j++) {
        if (f0 + j < F_) {
            float v = acc[j];
            v = (v >= 0.f) ? v : a * v;
            acc[j] = v;
            sum += v; ss += v * v;
        }
    }
    sum = wred_sum(sum); ss = wred_sum(ss);
    float mu = sum * (1.f / 2080.f);
    float var = ss * (1.f / 2080.f) - mu * mu;
    float rs = rsqrtf(var + EPS);
    size_t obase = (size_t)((h * B_ + b) * TC_ + t) * DV + (row & 31) * F_ + f0;
#pragma unroll
    for (int j = 0; j < 33; j++) {
        if (f0 + j < F_) {
            float gv = g[row * F_ + f0 + j];
            float bv = bet[row * F_ + f0 + j];
            out[obase + j] = f2bf((acc[j] - mu) * rs * gv + bv);
        }
    }
}

// ---------------- 3b. transpose V: [s][e] -> [e][s] (s padded 416, zeros) --
__global__ __launch_bounds__(256)
void transpose_v_kernel(const u16* __restrict__ Vf, u16* __restrict__ Vt) {
    __shared__ u16 tileb[32][33];
    int id = blockIdx.x;
    int sb = id % 13; id /= 13;
    int eb = id % 65; int hb = id / 65;
    const u16* src = Vf + (size_t)hb * TC_ * DV;
    u16* dst = Vt + (size_t)hb * DV * SP_;
    int j = threadIdx.x & 31, i0 = threadIdx.x >> 5;
#pragma unroll
    for (int k = 0; k < 4; k++) {
        int i = i0 + 8 * k;                 // s-local
        int s = sb * 32 + i, e = eb * 32 + j;
        u16 v = 0;
        if (s < TC_) v = src[(size_t)s * DV + e];
        tileb[i][j] = v;
    }
    __syncthreads();
#pragma unroll
    for (int k = 0; k < 4; k++) {
        int i2 = i0 + 8 * k;                // e-local
        int e = eb * 32 + i2, s = sb * 32 + j;
        dst[(size_t)e * SP_ + s] = tileb[j][i2];
    }
}

// ---------------- 4. MFMA attention: block per (h,b, 16 q rows) -----------
// QK^T in-register (C-layout), shuffle softmax, P->LDS bf16, PV as O^T=V^T.P^T
__global__ __launch_bounds__(256, 4)
void attn_kernel(const u16* __restrict__ Qf, const u16* __restrict__ Kf,
                 const u16* __restrict__ Vt, float* __restrict__ out) {
    __shared__ u16 qlds[16 * 552];          // Q tile, K-dim padded 544 (+8 bank pad)
    __shared__ u16 plds[16 * 424];          // P tile, s padded 416 (+8 bank pad)
    __shared__ float redmax[16 * 4];
    __shared__ float redsum[16 * 4];

    int tile = blockIdx.x % 63;
    int hb   = blockIdx.x / 63;             // h*4 + b
    int h = hb >> 2, b = hb & 3;
    int tid = threadIdx.x;
    int wave = tid >> 6, lane = tid & 63;
    int g = lane >> 4;                      // k-group (0..3)
    int n = lane & 15;
    int tq0 = tile * 16;

    // ---- stage Q tile into LDS (16 x 552, cols >=520 zero) ----
    const u16* qbase = Qf + (size_t)(hb * QROWS + tq0) * DQK;
    for (int i = tid; i < 16 * 69; i += 256) {
        int q = i / 69, cb = i % 69;
        uint4 val = make_uint4(0, 0, 0, 0);
        if (cb < 65) val = *(const uint4*)(qbase + (size_t)q * DQK + cb * 8);
        *(uint4*)(&qlds[q * 552 + cb * 8]) = val;
    }
    __syncthreads();

    // ---- QK^T: wave handles s-tiles tau = wave + 4i (tau < 26) ----
    f32x4 acc[7];
#pragma unroll
    for (int i = 0; i < 7; i++) acc[i] = (f32x4){0.f, 0.f, 0.f, 0.f};
    const u16* kslab = Kf + (size_t)hb * SP_ * DQKP;
    for (int c = 0; c < 17; c++) {
        bfrag aq = *(const bfrag*)(&qlds[n * 552 + c * 32 + g * 8]);
#pragma unroll
        for (int i = 0; i < 7; i++) {
            int tau = wave + 4 * i;
            if (tau < 26) {
                bfrag bk = *(const bfrag*)(kslab + (size_t)(tau * 16 + n) * DQKP + c * 32 + g * 8);
                acc[i] = __builtin_amdgcn_mfma_f32_16x16x32_bf16(aq, bk, acc[i], 0, 0, 0);
            }
        }
    }

    // ---- softmax over s (rows q = g*4+r live across 16-lane group + 4 waves)
    const float scale = 0.043852900965f;    // 1/sqrt(520)
    float m4[4], s4[4];
#pragma unroll
    for (int r = 0; r < 4; r++) {
        float mx = -1e30f;
#pragma unroll
        for (int i = 0; i < 7; i++) {
            int tau = wave + 4 * i;
            int s = tau * 16 + n;
            if (tau < 26 && s < TC_) mx = fmaxf(mx, acc[i][r] * scale);
        }
        mx = fmaxf(mx, __shfl_xor(mx, 1, 64));
        mx = fmaxf(mx, __shfl_xor(mx, 2, 64));
        mx = fmaxf(mx, __shfl_xor(mx, 4, 64));
        mx = fmaxf(mx, __shfl_xor(mx, 8, 64));
        m4[r] = mx;
    }
    if (n == 0) {
#pragma unroll
        for (int r = 0; r < 4; r++) redmax[(g * 4 + r) * 4 + wave] = m4[r];
    }
    __syncthreads();
#pragma unroll
    for (int r = 0; r < 4; r++) {
        int q = g * 4 + r;
        m4[r] = fmaxf(fmaxf(redmax[q * 4 + 0], redmax[q * 4 + 1]),
                      fmaxf(redmax[q * 4 + 2], redmax[q * 4 + 3]));
        s4[r] = 0.f;
    }
#pragma unroll
    for (int i = 0; i < 7; i++) {
        int tau = wave + 4 * i;
        if (tau < 26) {
            int s = tau * 16 + n;
#pragma unroll
            for (int r = 0; r < 4; r++) {
                float e = (s < TC_) ? __expf(acc[i][r] * scale - m4[r]) : 0.f;
                acc[i][r] = e;
                s4[r] += e;
            }
        }
    }
#pragma unroll
    for (int r = 0; r < 4; r++) {
        float sm = s4[r];
        sm += __shfl_xor(sm, 1, 64);
        sm += __shfl_xor(sm, 2, 64);
        sm += __shfl_xor(sm, 4, 64);
        sm += __shfl_xor(sm, 8, 64);
        s4[r] = sm;
    }
    if (n == 0) {
#pragma unroll
        for (int r = 0; r < 4; r++) redsum[(g * 4 + r) * 4 + wave] = s4[r];
    }
    __syncthreads();
#pragma unroll
    for (int r = 0; r < 4; r++) {
        int q = g * 4 + r;
        float tot = redsum[q * 4 + 0] + redsum[q * 4 + 1] + redsum[q * 4 + 2] + redsum[q * 4 + 3];
        s4[r] = 1.0f / tot;
    }
    // write P (bf16) to LDS: rows q, cols s (all 416 cols covered by tiles 0..25)
#pragma unroll
    for (int i = 0; i < 7; i++) {
        int tau = wave + 4 * i;
        if (tau < 26) {
            int s = tau * 16 + n;
#pragma unroll
            for (int r = 0; r < 4; r++) {
                plds[(g * 4 + r) * 424 + s] = f2bf(acc[i][r] * s4[r]);
            }
        }
    }
    __syncthreads();

    // ---- PV: O^T = V^T . P^T ; B-frags (P) preloaded, dv-tiles in pairs ----
    bfrag bp[13];
#pragma unroll
    for (int c = 0; c < 13; c++)
        bp[c] = *(const bfrag*)(&plds[n * 424 + c * 32 + g * 8]);

    const u16* vslab = Vt + (size_t)hb * DV * SP_;
    int t = tq0 + n;                        // output time index (col = q = n)
    for (int j = 0; j < 17; j++) {
        int p = wave + 4 * j;               // dv-pair index (wave-uniform)
        if (p >= 65) break;
        int e0 = p * 32;
        f32x4 a0 = (f32x4){0.f, 0.f, 0.f, 0.f};
        f32x4 a1 = (f32x4){0.f, 0.f, 0.f, 0.f};
#pragma unroll
        for (int c = 0; c < 13; c++) {
            bfrag v0 = *(const bfrag*)(vslab + (size_t)(e0 + n) * SP_ + c * 32 + g * 8);
            bfrag v1 = *(const bfrag*)(vslab + (size_t)(e0 + 16 + n) * SP_ + c * 32 + g * 8);
            a0 = __builtin_amdgcn_mfma_f32_16x16x32_bf16(v0, bp[c], a0, 0, 0, 0);
            a1 = __builtin_amdgcn_mfma_f32_16x16x32_bf16(v1, bp[c], a1, 0, 0, 0);
        }
        if (t < T_) {
#pragma unroll
            for (int r = 0; r < 4; r++) {
                int e = e0 + g * 4 + r;     // tile0 row
                int dh = e / F_, f = e - dh * F_;
                out[((size_t)(b * C_ + h * DH_ + dh) * T_ + t) * F_ + f] = a0[r];
                int e2 = e0 + 16 + g * 4 + r;
                int dh2 = e2 / F_, f2 = e2 - dh2 * F_;
                out[((size_t)(b * C_ + h * DH_ + dh2) * T_ + t) * F_ + f2] = a1[r];
            }
        }
    }
}

// ---------------- 4b. convert Wp to bf16 (once) ---------------------------
__global__ __launch_bounds__(256)
void wconv_kernel(const float* __restrict__ W, u16* __restrict__ Wbf) {
    int i = blockIdx.x * 256 + threadIdx.x;
    if (i < C_ * C_) Wbf[i] = f2bf(W[i]);
}

// ---------------- 5. projection via MFMA: conv1x1 + PReLU + LN(C,F) -------
// block per (b,t). GEMM: Y[e][f] = sum_c W[e][c] * X^T[f][c], M=128 K=128 N=65.
// X^T staged in LDS bf16 (rows f padded to 80, row stride 136 for banks);
// W read as bf16 frags from global (32 KB, L1/L2-resident).
// wave w owns e-tiles {2w, 2w+1} x all 5 f-tiles -> acc[2][5] (40 VGPR).
__global__ __launch_bounds__(256, 4)
void proj_mfma_kernel(float* __restrict__ io, const u16* __restrict__ Wbf,
                      const float* __restrict__ bpr, const float* __restrict__ apr,
                      const float* __restrict__ gpr, const float* __restrict__ betpr) {
    __shared__ u16 xt[80 * 136];
    __shared__ float wsum[4], wss[4];
    int b = blockIdx.x / T_, t = blockIdx.x % T_;
    int tid = threadIdx.x;
    size_t xbase = (size_t)(b * C_) * T_ * F_ + (size_t)t * F_;

    // stage X^T: coalesced fp32 reads over f, scattered u16 LDS writes
    for (int i = tid; i < C_ * F_; i += 256) {
        int c = i / F_, f = i % F_;
        xt[f * 136 + c] = f2bf(io[xbase + (size_t)c * T_ * F_ + f]);
    }
    // zero pad rows f = 65..79 (feed MFMA finite zeros; outputs masked)
    for (int i = tid; i < 15 * 128; i += 256) {
        int f = 65 + i / 128, c = i % 128;
        xt[f * 136 + c] = 0;
    }
    __syncthreads();

    int wave = tid >> 6, lane = tid & 63, g = lane >> 4, n = lane & 15;
    f32x4 acc[2][5];
#pragma unroll
    for (int a = 0; a < 2; a++)
#pragma unroll
        for (int ft = 0; ft < 5; ft++) acc[a][ft] = (f32x4){0.f, 0.f, 0.f, 0.f};

    // K loop: 4 chunks of 32. A = W rows (global bf16), B = X^T rows (LDS).
    for (int c32 = 0; c32 < 4; c32++) {
        bfrag aw0 = *(const bfrag*)(Wbf + (size_t)(wave * 32 + n) * C_ + c32 * 32 + g * 8);
        bfrag aw1 = *(const bfrag*)(Wbf + (size_t)(wave * 32 + 16 + n) * C_ + c32 * 32 + g * 8);
#pragma unroll
        for (int ft = 0; ft < 5; ft++) {
            bfrag bx = *(const bfrag*)(&xt[(ft * 16 + n) * 136 + c32 * 32 + g * 8]);
            acc[0][ft] = __builtin_amdgcn_mfma_f32_16x16x32_bf16(aw0, bx, acc[0][ft], 0, 0, 0);
            acc[1][ft] = __builtin_amdgcn_mfma_f32_16x16x32_bf16(aw1, bx, acc[1][ft], 0, 0, 0);
        }
    }

    // bias + PReLU + LN stats. acc[a][ft][r]: e = wave*32+a*16+g*4+r, f = ft*16+n
    float a_p = apr[0];
    float sum = 0.f, ss = 0.f;
#pragma unroll
    for (int a = 0; a < 2; a++) {
        int e0 = wave * 32 + a * 16 + g * 4;
#pragma unroll
        for (int r = 0; r < 4; r++) {
            float bb = bpr[e0 + r];
#pragma unroll
            for (int ft = 0; ft < 5; ft++) {
                float v = acc[a][ft][r] + bb;
                v = (v >= 0.f) ? v : a_p * v;
                acc[a][ft][r] = v;
                int f = ft * 16 + n;
                if (f < F_) { sum += v; ss += v * v; }
            }
        }
    }
    sum = wred_sum(sum); ss = wred_sum(ss);
    if (lane == 0) { wsum[wave] = sum; wss[wave] = ss; }
    __syncthreads();
    float tsum = wsum[0] + wsum[1] + wsum[2] + wsum[3];
    float tss  = wss[0] + wss[1] + wss[2] + wss[3];
    float mu = tsum * (1.f / 8320.f);
    float var = tss * (1.f / 8320.f) - mu * mu;
    float rs = rsqrtf(var + EPS);

#pragma unroll
    for (int a = 0; a < 2; a++) {
#pragma unroll
        for (int r = 0; r < 4; r++) {
            int e = wave * 32 + a * 16 + g * 4 + r;
#pragma unroll
            for (int ft = 0; ft < 5; ft++) {
                int f = ft * 16 + n;
                if (f < F_) {
                    io[((size_t)(b * C_ + e) * T_ + t) * F_ + f] =
                        (acc[a][ft][r] - mu) * rs * gpr[e * F_ + f] + betpr[e * F_ + f];
                }
            }
        }
    }
}

extern "C" void kernel_launch(void* const* d_in, const int* in_sizes, int n_in,
                              void* d_out, int out_size, void* d_ws, size_t ws_size,
                              hipStream_t stream) {
    const float* batch = (const float*)d_in[0];
    const float* pos   = (const float*)d_in[1];
    const float* neg   = (const float*)d_in[2];
    const float* WQ   = (const float*)d_in[3];
    const float* bQ   = (const float*)d_in[4];
    const float* aQ   = (const float*)d_in[5];
    const float* gQ   = (const float*)d_in[6];
    const float* betQ = (const float*)d_in[7];
    const float* WK   = (const float*)d_in[8];
    const float* bK   = (const float*)d_in[9];
    const float* aK   = (const float*)d_in[10];
    const float* gK   = (const float*)d_in[11];
    const float* betK = (const float*)d_in[12];
    const float* WV   = (const float*)d_in[13];
    const float* bV   = (const float*)d_in[14];
    const float* aV   = (const float*)d_in[15];
    const float* gV   = (const float*)d_in[16];
    const float* betV = (const float*)d_in[17];
    const float* Wp   = (const float*)d_in[18];
    const float* bp   = (const float*)d_in[19];
    const float* ap   = (const float*)d_in[20];
    const float* gp   = (const float*)d_in[21];
    const float* betp = (const float*)d_in[22];

    char* ws = (char*)d_ws;
    // layout (cond aliases Vt; cond is dead before transpose writes Vt):
    //   Vt   [0, 27,688,960)          16*2080*416*2
    //   Qf   [27,688,960, 44,462,080) 16*1008*520*2
    //   Kf   [44,462,080, 51,703,808) 16*416*544*2
    //   Vf   [51,703,808, 78,194,688) 16*398*2080*2
    //   Wbf aliases Vf start (Vf dead after transpose_v; Wbf written after it)
    u16* Vt   = (u16*)(ws);
    u16* cond = (u16*)(ws);
    u16* Qf   = (u16*)(ws + 27688960);
    u16* Kf   = (u16*)(ws + 44462080);
    u16* Vf   = (u16*)(ws + 51703808);
    u16* Wbf  = (u16*)(ws + 51703808);
    float* o  = (float*)d_out;

    const int NPOOL = B_ * C_ * TC_ * F_;
    pool_kernel<<<(NPOOL + 255) / 256, 256, 0, stream>>>(pos, neg, cond);
    qk_branch_kernel<float><<<B_ * T_,  256, 0, stream>>>(batch, T_,  QROWS, DQK,  WQ, bQ, aQ, gQ, betQ, Qf);
    qk_branch_kernel<u16>  <<<B_ * TC_, 256, 0, stream>>>(cond,  TC_, SP_,   DQKP, WK, bK, aK, gK, betK, Kf);
    v_branch_kernel <<<B_ * TC_, 256, 0, stream>>>(cond, WV, bV, aV, gV, betV, Vf);
    transpose_v_kernel<<<16 * 65 * 13, 256, 0, stream>>>(Vf, Vt);
    wconv_kernel<<<(C_ * C_ + 255) / 256, 256, 0, stream>>>(Wp, Wbf);
    attn_kernel<<<16 * 63, 256, 0, stream>>>(Qf, Kf, Vt, o);
    proj_mfma_kernel<<<B_ * T_, 256, 0, stream>>>(o, Wbf, bp, ap, gp, betp);
}

// Round 4
// 894.827 us; speedup vs baseline: 1.3389x; 1.0797x over previous
//
#include <hip/hip_runtime.h>
#include <hip/hip_bf16.h>

typedef unsigned short u16;
typedef __attribute__((ext_vector_type(8))) short bfrag;   // 8 bf16 = 4 VGPR
typedef __attribute__((ext_vector_type(4))) float f32x4;

#define B_ 4
#define C_ 128
#define T_ 1000
#define F_ 65
#define H_ 4
#define E_ 8
#define DH_ 32
#define TP_ 199
#define TC_ 398
#define DQK 520      // E*F
#define DQKP 544     // padded K-dim for MFMA (17 chunks of 32)
#define DV 2080      // DH*F
#define SP_ 416      // padded s (26 tiles of 16, 13 chunks of 32)
#define QROWS 1008   // padded T rows (63 tiles of 16)
#define EPS 1e-5f

__device__ __forceinline__ float bf2f(u16 u) {
    union { float f; unsigned int i; } v; v.i = ((unsigned int)u) << 16; return v.f;
}
__device__ __forceinline__ u16 f2bf(float f) {
    union { float f; unsigned int i; } v; v.f = f;
    unsigned int x = v.i;
    return (u16)((x + 0x7FFFu + ((x >> 16) & 1u)) >> 16);
}

__device__ __forceinline__ float wred_sum(float v) {
#pragma unroll
    for (int o = 32; o > 0; o >>= 1) v += __shfl_down(v, o, 64);
    return __shfl(v, 0, 64);
}

// ---------------- 0a. zero-fill Kf region (pad determinism) ---------------
__global__ __launch_bounds__(256)
void zerofill_kernel(uint4* __restrict__ dst, int n16) {
    int i = blockIdx.x * 256 + threadIdx.x;
    if (i < n16) dst[i] = make_uint4(0, 0, 0, 0);
}

// ---------------- 0b. W_Q/W_K/W_V -> split bf16 (hi + lo residual) --------
// layout (u16 idx): WQhi 0, WQlo 4096, WKhi 8192, WKlo 12288,
//                   WVhi 16384, WVlo 32768   (total 49,152 u16)
__global__ __launch_bounds__(256)
void wconv3_kernel(const float* __restrict__ WQ, const float* __restrict__ WK,
                   const float* __restrict__ WV, u16* __restrict__ dst) {
    int i = blockIdx.x * 256 + threadIdx.x;
    if (i >= 24576) return;
    float v; int hipos, lopos;
    if (i < 4096)      { v = WQ[i];        hipos = i;        lopos = i + 4096;  }
    else if (i < 8192) { v = WK[i - 4096]; hipos = i + 4096; lopos = i + 8192;  }
    else               { v = WV[i - 8192]; hipos = i + 8192; lopos = i + 24576; }
    u16 hi = f2bf(v);
    dst[hipos] = hi;
    dst[lopos] = f2bf(v - bf2f(hi));
}

// ---------------- 1. avg-pool along T + concat(+pos, -neg) ----------------
__global__ __launch_bounds__(256)
void pool_kernel(const float* __restrict__ pos, const float* __restrict__ neg,
                 u16* __restrict__ cond) {
    int idx = blockIdx.x * 256 + threadIdx.x;
    const int N = B_ * C_ * TC_ * F_;
    if (idx >= N) return;
    int f  = idx % F_;
    int tc = (idx / F_) % TC_;
    int c  = (idx / (F_ * TC_)) % C_;
    int b  = idx / (F_ * TC_ * C_);
    const float* src; float sign; int t0;
    if (tc < TP_) { src = pos; sign =  1.f; t0 = tc * 5; }
    else          { src = neg; sign = -1.f; t0 = (tc - TP_) * 5; }
    int base = ((b * C_ + c) * T_ + t0) * F_ + f;
    float s = 0.f;
#pragma unroll
    for (int k = 0; k < 10; k++) s += src[base + k * F_];
    cond[idx] = f2bf(s * (sign * 0.1f));
}

// ---------------- 2. Q/K branch via MFMA (split precision) ----------------
// block per (b,t). GEMM: Y[e][f] = sum_c W[e][c]*X^T[f][c], M=32 K=128 N=65.
// W = Whi + Wlo (bf16 pair). SPLITX: X = Xhi + Xlo (fp32 input, Q branch).
// conv = Whi*Xhi + Wlo*Xhi (+ Whi*Xlo)  -> ~fp32-exact.
// wave w: m-tile (w&1), f-group (w>>1). LN per head (8 rows x 65 f).
template <typename XT, bool SPLITX>
__global__ __launch_bounds__(256, 4)
void qk_mfma_kernel(const XT* __restrict__ x, int Tx, int rowsper, int ldout,
                    const u16* __restrict__ Wbf, const float* __restrict__ bias,
                    const float* __restrict__ alpha,
                    const float* __restrict__ g, const float* __restrict__ bet,
                    u16* __restrict__ out) {
    constexpr int XLO = 80 * 136;
    __shared__ u16 xt[(SPLITX ? 2 : 1) * 80 * 136];
    __shared__ float redS[8], redQ[8];
    int b = blockIdx.x / Tx, t = blockIdx.x % Tx;
    int tid = threadIdx.x;
    size_t xbase = (size_t)(b * C_) * Tx * F_ + (size_t)t * F_;
    for (int i = tid; i < C_ * F_; i += 256) {
        int c = i / F_, f = i % F_;
        if constexpr (SPLITX) {
            float v = (float)x[xbase + (size_t)c * Tx * F_ + f];
            u16 hi = f2bf(v);
            xt[f * 136 + c] = hi;
            xt[XLO + f * 136 + c] = f2bf(v - bf2f(hi));
        } else {
            xt[f * 136 + c] = (u16)x[xbase + (size_t)c * Tx * F_ + f];
        }
    }
    for (int i = tid; i < 15 * 128; i += 256) {
        xt[(65 + i / 128) * 136 + (i % 128)] = 0;
        if constexpr (SPLITX) xt[XLO + (65 + i / 128) * 136 + (i % 128)] = 0;
    }
    __syncthreads();

    int wave = tid >> 6, lane = tid & 63, gq = lane >> 4, n = lane & 15;
    int mt = wave & 1, fg = wave >> 1;
    int ftbase = fg ? 3 : 0;
    const int nft = 3;
    int jmax = fg ? 2 : 3;
    const u16* Wlo = Wbf + 32 * C_;
    f32x4 acc[3];
#pragma unroll
    for (int j = 0; j < nft; j++) acc[j] = (f32x4){0.f, 0.f, 0.f, 0.f};

    for (int c32 = 0; c32 < 4; c32++) {
        bfrag awh = *(const bfrag*)(Wbf + (size_t)(mt * 16 + n) * C_ + c32 * 32 + gq * 8);
        bfrag awl = *(const bfrag*)(Wlo + (size_t)(mt * 16 + n) * C_ + c32 * 32 + gq * 8);
#pragma unroll
        for (int j = 0; j < nft; j++) {
            if (j < jmax) {
                int boff = ((ftbase + j) * 16 + n) * 136 + c32 * 32 + gq * 8;
                bfrag bxh = *(const bfrag*)(&xt[boff]);
                acc[j] = __builtin_amdgcn_mfma_f32_16x16x32_bf16(awh, bxh, acc[j], 0, 0, 0);
                acc[j] = __builtin_amdgcn_mfma_f32_16x16x32_bf16(awl, bxh, acc[j], 0, 0, 0);
                if constexpr (SPLITX) {
                    bfrag bxl = *(const bfrag*)(&xt[XLO + boff]);
                    acc[j] = __builtin_amdgcn_mfma_f32_16x16x32_bf16(awh, bxl, acc[j], 0, 0, 0);
                }
            }
        }
    }

    int h = mt * 2 + (gq >> 1);
    int er0 = mt * 16 + gq * 4;
    float ap = alpha[h];
    float sum = 0.f, ss = 0.f;
#pragma unroll
    for (int j = 0; j < nft; j++) {
        if (j < jmax) {
#pragma unroll
            for (int r = 0; r < 4; r++) {
                float v = acc[j][r] + bias[er0 + r];
                v = (v >= 0.f) ? v : ap * v;
                acc[j][r] = v;
                int f = (ftbase + j) * 16 + n;
                if (f < F_) { sum += v; ss += v * v; }
            }
        }
    }
#pragma unroll
    for (int o = 1; o <= 8; o <<= 1) {
        sum += __shfl_xor(sum, o, 64);
        ss  += __shfl_xor(ss, o, 64);
    }
    sum += __shfl_xor(sum, 16, 64);
    ss  += __shfl_xor(ss, 16, 64);
    if (n == 0 && (gq & 1) == 0) { redS[h * 2 + fg] = sum; redQ[h * 2 + fg] = ss; }
    __syncthreads();
    float ts = redS[h * 2 + 0] + redS[h * 2 + 1];
    float tq = redQ[h * 2 + 0] + redQ[h * 2 + 1];
    float mu = ts * (1.f / 520.f);
    float var = tq * (1.f / 520.f) - mu * mu;
    float rs = rsqrtf(var + EPS);

    size_t obase = (size_t)((h * B_ + b) * rowsper + t) * ldout;
#pragma unroll
    for (int j = 0; j < nft; j++) {
        if (j < jmax) {
#pragma unroll
            for (int r = 0; r < 4; r++) {
                int f = (ftbase + j) * 16 + n;
                if (f < F_) {
                    int er = er0 + r;
                    int el = er & 7;
                    out[obase + el * F_ + f] =
                        f2bf((acc[j][r] - mu) * rs * g[er * F_ + f] + bet[er * F_ + f]);
                }
            }
        }
    }
}

// ---------------- 3. V branch via MFMA (split W) --------------------------
__global__ __launch_bounds__(256, 4)
void v_mfma_kernel(const u16* __restrict__ x, const u16* __restrict__ Wbf,
                   const float* __restrict__ bias, const float* __restrict__ alpha,
                   const float* __restrict__ g, const float* __restrict__ bet,
                   u16* __restrict__ out) {
    __shared__ u16 xt[80 * 136];
    int b = blockIdx.x / TC_, t = blockIdx.x % TC_;
    int tid = threadIdx.x;
    size_t xbase = (size_t)(b * C_) * TC_ * F_ + (size_t)t * F_;
    for (int i = tid; i < C_ * F_; i += 256) {
        int c = i / F_, f = i % F_;
        xt[f * 136 + c] = x[xbase + (size_t)c * TC_ * F_ + f];
    }
    for (int i = tid; i < 15 * 128; i += 256)
        xt[(65 + i / 128) * 136 + (i % 128)] = 0;
    __syncthreads();

    int wave = tid >> 6, lane = tid & 63, gq = lane >> 4, n = lane & 15;
    const u16* Wlo = Wbf + 128 * C_;
    f32x4 acc[2][5];
#pragma unroll
    for (int a = 0; a < 2; a++)
#pragma unroll
        for (int ft = 0; ft < 5; ft++) acc[a][ft] = (f32x4){0.f, 0.f, 0.f, 0.f};

    for (int c32 = 0; c32 < 4; c32++) {
        bfrag aw0h = *(const bfrag*)(Wbf + (size_t)(wave * 32 + n) * C_ + c32 * 32 + gq * 8);
        bfrag aw0l = *(const bfrag*)(Wlo + (size_t)(wave * 32 + n) * C_ + c32 * 32 + gq * 8);
        bfrag aw1h = *(const bfrag*)(Wbf + (size_t)(wave * 32 + 16 + n) * C_ + c32 * 32 + gq * 8);
        bfrag aw1l = *(const bfrag*)(Wlo + (size_t)(wave * 32 + 16 + n) * C_ + c32 * 32 + gq * 8);
#pragma unroll
        for (int ft = 0; ft < 5; ft++) {
            bfrag bx = *(const bfrag*)(&xt[(ft * 16 + n) * 136 + c32 * 32 + gq * 8]);
            acc[0][ft] = __builtin_amdgcn_mfma_f32_16x16x32_bf16(aw0h, bx, acc[0][ft], 0, 0, 0);
            acc[0][ft] = __builtin_amdgcn_mfma_f32_16x16x32_bf16(aw0l, bx, acc[0][ft], 0, 0, 0);
            acc[1][ft] = __builtin_amdgcn_mfma_f32_16x16x32_bf16(aw1h, bx, acc[1][ft], 0, 0, 0);
            acc[1][ft] = __builtin_amdgcn_mfma_f32_16x16x32_bf16(aw1l, bx, acc[1][ft], 0, 0, 0);
        }
    }

    int h = wave;
    float ap = alpha[h];
    float sum = 0.f, ss = 0.f;
#pragma unroll
    for (int a = 0; a < 2; a++) {
        int er0 = wave * 32 + a * 16 + gq * 4;
#pragma unroll
        for (int r = 0; r < 4; r++) {
            float bb = bias[er0 + r];
#pragma unroll
            for (int ft = 0; ft < 5; ft++) {
                float v = acc[a][ft][r] + bb;
                v = (v >= 0.f) ? v : ap * v;
                acc[a][ft][r] = v;
                int f = ft * 16 + n;
                if (f < F_) { sum += v; ss += v * v; }
            }
        }
    }
    sum = wred_sum(sum); ss = wred_sum(ss);
    float mu = sum * (1.f / 2080.f);
    float var = ss * (1.f / 2080.f) - mu * mu;
    float rs = rsqrtf(var + EPS);

    size_t obase = (size_t)((h * B_ + b) * TC_ + t) * DV;
#pragma unroll
    for (int a = 0; a < 2; a++) {
#pragma unroll
        for (int r = 0; r < 4; r++) {
            int er = wave * 32 + a * 16 + gq * 4 + r;
            int drow = er & 31;
#pragma unroll
            for (int ft = 0; ft < 5; ft++) {
                int f = ft * 16 + n;
                if (f < F_) {
                    out[obase + drow * F_ + f] =
                        f2bf((acc[a][ft][r] - mu) * rs * g[er * F_ + f] + bet[er * F_ + f]);
                }
            }
        }
    }
}

// ---------------- 3b. transpose V: [s][e] -> [e][s] (s padded 416, zeros) --
__global__ __launch_bounds__(256)
void transpose_v_kernel(const u16* __restrict__ Vf, u16* __restrict__ Vt) {
    __shared__ u16 tileb[32][33];
    int id = blockIdx.x;
    int sb = id % 13; id /= 13;
    int eb = id % 65; int hb = id / 65;
    const u16* src = Vf + (size_t)hb * TC_ * DV;
    u16* dst = Vt + (size_t)hb * DV * SP_;
    int j = threadIdx.x & 31, i0 = threadIdx.x >> 5;
#pragma unroll
    for (int k = 0; k < 4; k++) {
        int i = i0 + 8 * k;                 // s-local
        int s = sb * 32 + i, e = eb * 32 + j;
        u16 v = 0;
        if (s < TC_) v = src[(size_t)s * DV + e];
        tileb[i][j] = v;
    }
    __syncthreads();
#pragma unroll
    for (int k = 0; k < 4; k++) {
        int i2 = i0 + 8 * k;                // e-local
        int e = eb * 32 + i2, s = sb * 32 + j;
        dst[(size_t)e * SP_ + s] = tileb[j][i2];
    }
}

// ---------------- 4. MFMA attention: block per (h,b, 16 q rows) -----------
__global__ __launch_bounds__(256, 4)
void attn_kernel(const u16* __restrict__ Qf, const u16* __restrict__ Kf,
                 const u16* __restrict__ Vt, float* __restrict__ out) {
    __shared__ u16 qlds[16 * 552];          // Q tile, K-dim padded 544 (+8 bank pad)
    __shared__ u16 plds[16 * 424];          // P tile, s padded 416 (+8 bank pad)
    __shared__ float redmax[16 * 4];
    __shared__ float redsum[16 * 4];

    int tile = blockIdx.x % 63;
    int hb   = blockIdx.x / 63;             // h*4 + b
    int h = hb >> 2, b = hb & 3;
    int tid = threadIdx.x;
    int wave = tid >> 6, lane = tid & 63;
    int g = lane >> 4;                      // k-group (0..3)
    int n = lane & 15;
    int tq0 = tile * 16;

    // ---- stage Q tile into LDS (16 x 552, cols >=520 zero) ----
    const u16* qbase = Qf + (size_t)(hb * QROWS + tq0) * DQK;
    for (int i = tid; i < 16 * 69; i += 256) {
        int q = i / 69, cb = i % 69;
        uint4 val = make_uint4(0, 0, 0, 0);
        if (cb < 65) val = *(const uint4*)(qbase + (size_t)q * DQK + cb * 8);
        *(uint4*)(&qlds[q * 552 + cb * 8]) = val;
    }
    __syncthreads();

    // ---- QK^T: wave handles s-tiles tau = wave + 4i (tau < 26) ----
    f32x4 acc[7];
#pragma unroll
    for (int i = 0; i < 7; i++) acc[i] = (f32x4){0.f, 0.f, 0.f, 0.f};
    const u16* kslab = Kf + (size_t)hb * SP_ * DQKP;
    for (int c = 0; c < 17; c++) {
        bfrag aq = *(const bfrag*)(&qlds[n * 552 + c * 32 + g * 8]);
#pragma unroll
        for (int i = 0; i < 7; i++) {
            int tau = wave + 4 * i;
            if (tau < 26) {
                bfrag bk = *(const bfrag*)(kslab + (size_t)(tau * 16 + n) * DQKP + c * 32 + g * 8);
                acc[i] = __builtin_amdgcn_mfma_f32_16x16x32_bf16(aq, bk, acc[i], 0, 0, 0);
            }
        }
    }

    // ---- softmax over s (rows q = g*4+r live across 16-lane group + 4 waves)
    const float scale = 0.043852900965f;    // 1/sqrt(520)
    float m4[4], s4[4];
#pragma unroll
    for (int r = 0; r < 4; r++) {
        float mx = -1e30f;
#pragma unroll
        for (int i = 0; i < 7; i++) {
            int tau = wave + 4 * i;
            int s = tau * 16 + n;
            if (tau < 26 && s < TC_) mx = fmaxf(mx, acc[i][r] * scale);
        }
        mx = fmaxf(mx, __shfl_xor(mx, 1, 64));
        mx = fmaxf(mx, __shfl_xor(mx, 2, 64));
        mx = fmaxf(mx, __shfl_xor(mx, 4, 64));
        mx = fmaxf(mx, __shfl_xor(mx, 8, 64));
        m4[r] = mx;
    }
    if (n == 0) {
#pragma unroll
        for (int r = 0; r < 4; r++) redmax[(g * 4 + r) * 4 + wave] = m4[r];
    }
    __syncthreads();
#pragma unroll
    for (int r = 0; r < 4; r++) {
        int q = g * 4 + r;
        m4[r] = fmaxf(fmaxf(redmax[q * 4 + 0], redmax[q * 4 + 1]),
                      fmaxf(redmax[q * 4 + 2], redmax[q * 4 + 3]));
        s4[r] = 0.f;
    }
#pragma unroll
    for (int i = 0; i < 7; i++) {
        int tau = wave + 4 * i;
        if (tau < 26) {
            int s = tau * 16 + n;
#pragma unroll
            for (int r = 0; r < 4; r++) {
                float e = (s < TC_) ? __expf(acc[i][r] * scale - m4[r]) : 0.f;
                acc[i][r] = e;
                s4[r] += e;
            }
        }
    }
#pragma unroll
    for (int r = 0; r < 4; r++) {
        float sm = s4[r];
        sm += __shfl_xor(sm, 1, 64);
        sm += __shfl_xor(sm, 2, 64);
        sm += __shfl_xor(sm, 4, 64);
        sm += __shfl_xor(sm, 8, 64);
        s4[r] = sm;
    }
    if (n == 0) {
#pragma unroll
        for (int r = 0; r < 4; r++) redsum[(g * 4 + r) * 4 + wave] = s4[r];
    }
    __syncthreads();
#pragma unroll
    for (int r = 0; r < 4; r++) {
        int q = g * 4 + r;
        float tot = redsum[q * 4 + 0] + redsum[q * 4 + 1] + redsum[q * 4 + 2] + redsum[q * 4 + 3];
        s4[r] = 1.0f / tot;
    }
#pragma unroll
    for (int i = 0; i < 7; i++) {
        int tau = wave + 4 * i;
        if (tau < 26) {
            int s = tau * 16 + n;
#pragma unroll
            for (int r = 0; r < 4; r++) {
                plds[(g * 4 + r) * 424 + s] = f2bf(acc[i][r] * s4[r]);
            }
        }
    }
    __syncthreads();

    // ---- PV: O^T = V^T . P^T ; B-frags (P) preloaded, dv-tiles in pairs ----
    bfrag bp[13];
#pragma unroll
    for (int c = 0; c < 13; c++)
        bp[c] = *(const bfrag*)(&plds[n * 424 + c * 32 + g * 8]);

    const u16* vslab = Vt + (size_t)hb * DV * SP_;
    int t = tq0 + n;                        // output time index (col = q = n)
    for (int j = 0; j < 17; j++) {
        int p = wave + 4 * j;               // dv-pair index (wave-uniform)
        if (p >= 65) break;
        int e0 = p * 32;
        f32x4 a0 = (f32x4){0.f, 0.f, 0.f, 0.f};
        f32x4 a1 = (f32x4){0.f, 0.f, 0.f, 0.f};
#pragma unroll
        for (int c = 0; c < 13; c++) {
            bfrag v0 = *(const bfrag*)(vslab + (size_t)(e0 + n) * SP_ + c * 32 + g * 8);
            bfrag v1 = *(const bfrag*)(vslab + (size_t)(e0 + 16 + n) * SP_ + c * 32 + g * 8);
            a0 = __builtin_amdgcn_mfma_f32_16x16x32_bf16(v0, bp[c], a0, 0, 0, 0);
            a1 = __builtin_amdgcn_mfma_f32_16x16x32_bf16(v1, bp[c], a1, 0, 0, 0);
        }
        if (t < T_) {
#pragma unroll
            for (int r = 0; r < 4; r++) {
                int e = e0 + g * 4 + r;     // tile0 row
                int dh = e / F_, f = e - dh * F_;
                out[((size_t)(b * C_ + h * DH_ + dh) * T_ + t) * F_ + f] = a0[r];
                int e2 = e0 + 16 + g * 4 + r;
                int dh2 = e2 / F_, f2 = e2 - dh2 * F_;
                out[((size_t)(b * C_ + h * DH_ + dh2) * T_ + t) * F_ + f2] = a1[r];
            }
        }
    }
}

// ---------------- 4b. convert Wp to split bf16 (hi, lo) -------------------
__global__ __launch_bounds__(256)
void wconv_kernel(const float* __restrict__ W, u16* __restrict__ Wbf) {
    int i = blockIdx.x * 256 + threadIdx.x;
    if (i < C_ * C_) {
        float v = W[i];
        u16 hi = f2bf(v);
        Wbf[i] = hi;
        Wbf[C_ * C_ + i] = f2bf(v - bf2f(hi));
    }
}

// ---------------- 5. projection via MFMA (split W) ------------------------
__global__ __launch_bounds__(256, 4)
void proj_mfma_kernel(float* __restrict__ io, const u16* __restrict__ Wbf,
                      const float* __restrict__ bpr, const float* __restrict__ apr,
                      const float* __restrict__ gpr, const float* __restrict__ betpr) {
    __shared__ u16 xt[80 * 136];
    __shared__ float wsum[4], wss[4];
    int b = blockIdx.x / T_, t = blockIdx.x % T_;
    int tid = threadIdx.x;
    size_t xbase = (size_t)(b * C_) * T_ * F_ + (size_t)t * F_;

    for (int i = tid; i < C_ * F_; i += 256) {
        int c = i / F_, f = i % F_;
        xt[f * 136 + c] = f2bf(io[xbase + (size_t)c * T_ * F_ + f]);
    }
    for (int i = tid; i < 15 * 128; i += 256) {
        int f = 65 + i / 128, c = i % 128;
        xt[f * 136 + c] = 0;
    }
    __syncthreads();

    int wave = tid >> 6, lane = tid & 63, g = lane >> 4, n = lane & 15;
    const u16* Wlo = Wbf + C_ * C_;
    f32x4 acc[2][5];
#pragma unroll
    for (int a = 0; a < 2; a++)
#pragma unroll
        for (int ft = 0; ft < 5; ft++) acc[a][ft] = (f32x4){0.f, 0.f, 0.f, 0.f};

    for (int c32 = 0; c32 < 4; c32++) {
        bfrag aw0h = *(const bfrag*)(Wbf + (size_t)(wave * 32 + n) * C_ + c32 * 32 + g * 8);
        bfrag aw0l = *(const bfrag*)(Wlo + (size_t)(wave * 32 + n) * C_ + c32 * 32 + g * 8);
        bfrag aw1h = *(const bfrag*)(Wbf + (size_t)(wave * 32 + 16 + n) * C_ + c32 * 32 + g * 8);
        bfrag aw1l = *(const bfrag*)(Wlo + (size_t)(wave * 32 + 16 + n) * C_ + c32 * 32 + g * 8);
#pragma unroll
        for (int ft = 0; ft < 5; ft++) {
            bfrag bx = *(const bfrag*)(&xt[(ft * 16 + n) * 136 + c32 * 32 + g * 8]);
            acc[0][ft] = __builtin_amdgcn_mfma_f32_16x16x32_bf16(aw0h, bx, acc[0][ft], 0, 0, 0);
            acc[0][ft] = __builtin_amdgcn_mfma_f32_16x16x32_bf16(aw0l, bx, acc[0][ft], 0, 0, 0);
            acc[1][ft] = __builtin_amdgcn_mfma_f32_16x16x32_bf16(aw1h, bx, acc[1][ft], 0, 0, 0);
            acc[1][ft] = __builtin_amdgcn_mfma_f32_16x16x32_bf16(aw1l, bx, acc[1][ft], 0, 0, 0);
        }
    }

    float a_p = apr[0];
    float sum = 0.f, ss = 0.f;
#pragma unroll
    for (int a = 0; a < 2; a++) {
        int e0 = wave * 32 + a * 16 + g * 4;
#pragma unroll
        for (int r = 0; r < 4; r++) {
            float bb = bpr[e0 + r];
#pragma unroll
            for (int ft = 0; ft < 5; ft++) {
                float v = acc[a][ft][r] + bb;
                v = (v >= 0.f) ? v : a_p * v;
                acc[a][ft][r] = v;
                int f = ft * 16 + n;
                if (f < F_) { sum += v; ss += v * v; }
            }
        }
    }
    sum = wred_sum(sum); ss = wred_sum(ss);
    if (lane == 0) { wsum[wave] = sum; wss[wave] = ss; }
    __syncthreads();
    float tsum = wsum[0] + wsum[1] + wsum[2] + wsum[3];
    float tss  = wss[0] + wss[1] + wss[2] + wss[3];
    float mu = tsum * (1.f / 8320.f);
    float var = tss * (1.f / 8320.f) - mu * mu;
    float rs = rsqrtf(var + EPS);

#pragma unroll
    for (int a = 0; a < 2; a++) {
#pragma unroll
        for (int r = 0; r < 4; r++) {
            int e = wave * 32 + a * 16 + g * 4 + r;
#pragma unroll
            for (int ft = 0; ft < 5; ft++) {
                int f = ft * 16 + n;
                if (f < F_) {
                    io[((size_t)(b * C_ + e) * T_ + t) * F_ + f] =
                        (acc[a][ft][r] - mu) * rs * gpr[e * F_ + f] + betpr[e * F_ + f];
                }
            }
        }
    }
}

extern "C" void kernel_launch(void* const* d_in, const int* in_sizes, int n_in,
                              void* d_out, int out_size, void* d_ws, size_t ws_size,
                              hipStream_t stream) {
    const float* batch = (const float*)d_in[0];
    const float* pos   = (const float*)d_in[1];
    const float* neg   = (const float*)d_in[2];
    const float* WQ   = (const float*)d_in[3];
    const float* bQ   = (const float*)d_in[4];
    const float* aQ   = (const float*)d_in[5];
    const float* gQ   = (const float*)d_in[6];
    const float* betQ = (const float*)d_in[7];
    const float* WK   = (const float*)d_in[8];
    const float* bK   = (const float*)d_in[9];
    const float* aK   = (const float*)d_in[10];
    const float* gK   = (const float*)d_in[11];
    const float* betK = (const float*)d_in[12];
    const float* WV   = (const float*)d_in[13];
    const float* bV   = (const float*)d_in[14];
    const float* aV   = (const float*)d_in[15];
    const float* gV   = (const float*)d_in[16];
    const float* betV = (const float*)d_in[17];
    const float* Wp   = (const float*)d_in[18];
    const float* bp   = (const float*)d_in[19];
    const float* ap   = (const float*)d_in[20];
    const float* gp   = (const float*)d_in[21];
    const float* betp = (const float*)d_in[22];

    char* ws = (char*)d_ws;
    // layout (cond aliases Vt; cond is dead before transpose writes Vt):
    //   Vt   [0, 27,688,960)          16*2080*416*2
    //     cond  [0, 26,490,880)       aliases Vt head (dead before transpose)
    //     Wqkv  [26,490,880, 26,589,184)  split bf16 W (49,152 u16), dead before transpose
    //   Qf   [27,688,960, 44,462,080) 16*1008*520*2
    //   Kf   [44,462,080, 51,703,808) 16*416*544*2
    //   Vf   [51,703,808, 78,194,688) 16*398*2080*2
    //   Wpbf aliases Vf start (Vf dead after transpose_v); hi+lo = 65,536 B
    u16* Vt   = (u16*)(ws);
    u16* cond = (u16*)(ws);
    u16* Wqkv = (u16*)(ws + 26490880);
    u16* Qf   = (u16*)(ws + 27688960);
    u16* Kf   = (u16*)(ws + 44462080);
    u16* Vf   = (u16*)(ws + 51703808);
    u16* Wpbf = (u16*)(ws + 51703808);
    u16* WQbf = Wqkv;            // hi at 0, lo at +4096
    u16* WKbf = Wqkv + 8192;     // hi, lo at +4096
    u16* WVbf = Wqkv + 16384;    // hi, lo at +16384
    float* o  = (float*)d_out;

    wconv3_kernel<<<96, 256, 0, stream>>>(WQ, WK, WV, Wqkv);
    const int NPOOL = B_ * C_ * TC_ * F_;
    pool_kernel<<<(NPOOL + 255) / 256, 256, 0, stream>>>(pos, neg, cond);
    const int KF16 = (16 * SP_ * DQKP * 2) / 16;   // uint4 count = 452,608
    zerofill_kernel<<<(KF16 + 255) / 256, 256, 0, stream>>>((uint4*)Kf, KF16);
    qk_mfma_kernel<float, true><<<B_ * T_,  256, 0, stream>>>(batch, T_,  QROWS, DQK,  WQbf, bQ, aQ, gQ, betQ, Qf);
    qk_mfma_kernel<u16, false> <<<B_ * TC_, 256, 0, stream>>>(cond,  TC_, SP_,   DQKP, WKbf, bK, aK, gK, betK, Kf);
    v_mfma_kernel<<<B_ * TC_, 256, 0, stream>>>(cond, WVbf, bV, aV, gV, betV, Vf);
    transpose_v_kernel<<<16 * 65 * 13, 256, 0, stream>>>(Vf, Vt);
    wconv_kernel<<<(C_ * C_ + 255) / 256, 256, 0, stream>>>(Wp, Wpbf);
    attn_kernel<<<16 * 63, 256, 0, stream>>>(Qf, Kf, Vt, o);
    proj_mfma_kernel<<<B_ * T_, 256, 0, stream>>>(o, Wpbf, bp, ap, gp, betp);
}

// Round 5
// 867.970 us; speedup vs baseline: 1.3803x; 1.0309x over previous
//
#include <hip/hip_runtime.h>
#include <hip/hip_bf16.h>

typedef unsigned short u16;
typedef __attribute__((ext_vector_type(8))) short bfrag;   // 8 bf16 = 4 VGPR
typedef __attribute__((ext_vector_type(4))) float f32x4;

#define B_ 4
#define C_ 128
#define T_ 1000
#define F_ 65
#define H_ 4
#define E_ 8
#define DH_ 32
#define TP_ 199
#define TC_ 398
#define DQK 520      // E*F
#define DQKP 544     // padded K-dim for MFMA (17 chunks of 32)
#define DV 2080      // DH*F
#define SP_ 416      // padded s (26 tiles of 16, 13 chunks of 32)
#define QROWS 1008   // padded T rows
#define VTP 13312    // u16 per (hb,p) V block: 13 c * 2 eh * 64 lane * 8
#define EPS 1e-5f

__device__ __forceinline__ float bf2f(u16 u) {
    union { float f; unsigned int i; } v; v.i = ((unsigned int)u) << 16; return v.f;
}
__device__ __forceinline__ u16 f2bf(float f) {
    union { float f; unsigned int i; } v; v.f = f;
    unsigned int x = v.i;
    return (u16)((x + 0x7FFFu + ((x >> 16) & 1u)) >> 16);
}

__device__ __forceinline__ float wred_sum(float v) {
#pragma unroll
    for (int o = 32; o > 0; o >>= 1) v += __shfl_down(v, o, 64);
    return __shfl(v, 0, 64);
}

// ---------------- 0a. zero-fill Kf region (pad determinism) ---------------
__global__ __launch_bounds__(256)
void zerofill_kernel(uint4* __restrict__ dst, int n16) {
    int i = blockIdx.x * 256 + threadIdx.x;
    if (i < n16) dst[i] = make_uint4(0, 0, 0, 0);
}

// ---------------- 0b. W_Q/W_K/W_V -> split bf16 (hi + lo residual) --------
__global__ __launch_bounds__(256)
void wconv3_kernel(const float* __restrict__ WQ, const float* __restrict__ WK,
                   const float* __restrict__ WV, u16* __restrict__ dst) {
    int i = blockIdx.x * 256 + threadIdx.x;
    if (i >= 24576) return;
    float v; int hipos, lopos;
    if (i < 4096)      { v = WQ[i];        hipos = i;        lopos = i + 4096;  }
    else if (i < 8192) { v = WK[i - 4096]; hipos = i + 4096; lopos = i + 8192;  }
    else               { v = WV[i - 8192]; hipos = i + 8192; lopos = i + 24576; }
    u16 hi = f2bf(v);
    dst[hipos] = hi;
    dst[lopos] = f2bf(v - bf2f(hi));
}

// ---------------- 1. avg-pool along T + concat(+pos, -neg) ----------------
__global__ __launch_bounds__(256)
void pool_kernel(const float* __restrict__ pos, const float* __restrict__ neg,
                 u16* __restrict__ cond) {
    int idx = blockIdx.x * 256 + threadIdx.x;
    const int N = B_ * C_ * TC_ * F_;
    if (idx >= N) return;
    int f  = idx % F_;
    int tc = (idx / F_) % TC_;
    int c  = (idx / (F_ * TC_)) % C_;
    int b  = idx / (F_ * TC_ * C_);
    const float* src; float sign; int t0;
    if (tc < TP_) { src = pos; sign =  1.f; t0 = tc * 5; }
    else          { src = neg; sign = -1.f; t0 = (tc - TP_) * 5; }
    int base = ((b * C_ + c) * T_ + t0) * F_ + f;
    float s = 0.f;
#pragma unroll
    for (int k = 0; k < 10; k++) s += src[base + k * F_];
    cond[idx] = f2bf(s * (sign * 0.1f));
}

// ---------------- 2. Q/K branch via MFMA (split precision) ----------------
template <typename XT, bool SPLITX>
__global__ __launch_bounds__(256, 4)
void qk_mfma_kernel(const XT* __restrict__ x, int Tx, int rowsper, int ldout,
                    const u16* __restrict__ Wbf, const float* __restrict__ bias,
                    const float* __restrict__ alpha,
                    const float* __restrict__ g, const float* __restrict__ bet,
                    u16* __restrict__ out) {
    constexpr int XLO = 80 * 136;
    __shared__ u16 xt[(SPLITX ? 2 : 1) * 80 * 136];
    __shared__ float redS[8], redQ[8];
    int b = blockIdx.x / Tx, t = blockIdx.x % Tx;
    int tid = threadIdx.x;
    size_t xbase = (size_t)(b * C_) * Tx * F_ + (size_t)t * F_;
    for (int i = tid; i < C_ * F_; i += 256) {
        int c = i / F_, f = i % F_;
        if constexpr (SPLITX) {
            float v = (float)x[xbase + (size_t)c * Tx * F_ + f];
            u16 hi = f2bf(v);
            xt[f * 136 + c] = hi;
            xt[XLO + f * 136 + c] = f2bf(v - bf2f(hi));
        } else {
            xt[f * 136 + c] = (u16)x[xbase + (size_t)c * Tx * F_ + f];
        }
    }
    for (int i = tid; i < 15 * 128; i += 256) {
        xt[(65 + i / 128) * 136 + (i % 128)] = 0;
        if constexpr (SPLITX) xt[XLO + (65 + i / 128) * 136 + (i % 128)] = 0;
    }
    __syncthreads();

    int wave = tid >> 6, lane = tid & 63, gq = lane >> 4, n = lane & 15;
    int mt = wave & 1, fg = wave >> 1;
    int ftbase = fg ? 3 : 0;
    const int nft = 3;
    int jmax = fg ? 2 : 3;
    const u16* Wlo = Wbf + 32 * C_;
    f32x4 acc[3];
#pragma unroll
    for (int j = 0; j < nft; j++) acc[j] = (f32x4){0.f, 0.f, 0.f, 0.f};

    for (int c32 = 0; c32 < 4; c32++) {
        bfrag awh = *(const bfrag*)(Wbf + (size_t)(mt * 16 + n) * C_ + c32 * 32 + gq * 8);
        bfrag awl = *(const bfrag*)(Wlo + (size_t)(mt * 16 + n) * C_ + c32 * 32 + gq * 8);
#pragma unroll
        for (int j = 0; j < nft; j++) {
            if (j < jmax) {
                int boff = ((ftbase + j) * 16 + n) * 136 + c32 * 32 + gq * 8;
                bfrag bxh = *(const bfrag*)(&xt[boff]);
                acc[j] = __builtin_amdgcn_mfma_f32_16x16x32_bf16(awh, bxh, acc[j], 0, 0, 0);
                acc[j] = __builtin_amdgcn_mfma_f32_16x16x32_bf16(awl, bxh, acc[j], 0, 0, 0);
                if constexpr (SPLITX) {
                    bfrag bxl = *(const bfrag*)(&xt[XLO + boff]);
                    acc[j] = __builtin_amdgcn_mfma_f32_16x16x32_bf16(awh, bxl, acc[j], 0, 0, 0);
                }
            }
        }
    }

    int h = mt * 2 + (gq >> 1);
    int er0 = mt * 16 + gq * 4;
    float ap = alpha[h];
    float sum = 0.f, ss = 0.f;
#pragma unroll
    for (int j = 0; j < nft; j++) {
        if (j < jmax) {
#pragma unroll
            for (int r = 0; r < 4; r++) {
                float v = acc[j][r] + bias[er0 + r];
                v = (v >= 0.f) ? v : ap * v;
                acc[j][r] = v;
                int f = (ftbase + j) * 16 + n;
                if (f < F_) { sum += v; ss += v * v; }
            }
        }
    }
#pragma unroll
    for (int o = 1; o <= 8; o <<= 1) {
        sum += __shfl_xor(sum, o, 64);
        ss  += __shfl_xor(ss, o, 64);
    }
    sum += __shfl_xor(sum, 16, 64);
    ss  += __shfl_xor(ss, 16, 64);
    if (n == 0 && (gq & 1) == 0) { redS[h * 2 + fg] = sum; redQ[h * 2 + fg] = ss; }
    __syncthreads();
    float ts = redS[h * 2 + 0] + redS[h * 2 + 1];
    float tq = redQ[h * 2 + 0] + redQ[h * 2 + 1];
    float mu = ts * (1.f / 520.f);
    float var = tq * (1.f / 520.f) - mu * mu;
    float rs = rsqrtf(var + EPS);

    size_t obase = (size_t)((h * B_ + b) * rowsper + t) * ldout;
#pragma unroll
    for (int j = 0; j < nft; j++) {
        if (j < jmax) {
#pragma unroll
            for (int r = 0; r < 4; r++) {
                int f = (ftbase + j) * 16 + n;
                if (f < F_) {
                    int er = er0 + r;
                    int el = er & 7;
                    out[obase + el * F_ + f] =
                        f2bf((acc[j][r] - mu) * rs * g[er * F_ + f] + bet[er * F_ + f]);
                }
            }
        }
    }
}

// ---------------- 3. V branch via MFMA (split W) --------------------------
__global__ __launch_bounds__(256, 4)
void v_mfma_kernel(const u16* __restrict__ x, const u16* __restrict__ Wbf,
                   const float* __restrict__ bias, const float* __restrict__ alpha,
                   const float* __restrict__ g, const float* __restrict__ bet,
                   u16* __restrict__ out) {
    __shared__ u16 xt[80 * 136];
    int b = blockIdx.x / TC_, t = blockIdx.x % TC_;
    int tid = threadIdx.x;
    size_t xbase = (size_t)(b * C_) * TC_ * F_ + (size_t)t * F_;
    for (int i = tid; i < C_ * F_; i += 256) {
        int c = i / F_, f = i % F_;
        xt[f * 136 + c] = x[xbase + (size_t)c * TC_ * F_ + f];
    }
    for (int i = tid; i < 15 * 128; i += 256)
        xt[(65 + i / 128) * 136 + (i % 128)] = 0;
    __syncthreads();

    int wave = tid >> 6, lane = tid & 63, gq = lane >> 4, n = lane & 15;
    const u16* Wlo = Wbf + 128 * C_;
    f32x4 acc[2][5];
#pragma unroll
    for (int a = 0; a < 2; a++)
#pragma unroll
        for (int ft = 0; ft < 5; ft++) acc[a][ft] = (f32x4){0.f, 0.f, 0.f, 0.f};

    for (int c32 = 0; c32 < 4; c32++) {
        bfrag aw0h = *(const bfrag*)(Wbf + (size_t)(wave * 32 + n) * C_ + c32 * 32 + gq * 8);
        bfrag aw0l = *(const bfrag*)(Wlo + (size_t)(wave * 32 + n) * C_ + c32 * 32 + gq * 8);
        bfrag aw1h = *(const bfrag*)(Wbf + (size_t)(wave * 32 + 16 + n) * C_ + c32 * 32 + gq * 8);
        bfrag aw1l = *(const bfrag*)(Wlo + (size_t)(wave * 32 + 16 + n) * C_ + c32 * 32 + gq * 8);
#pragma unroll
        for (int ft = 0; ft < 5; ft++) {
            bfrag bx = *(const bfrag*)(&xt[(ft * 16 + n) * 136 + c32 * 32 + gq * 8]);
            acc[0][ft] = __builtin_amdgcn_mfma_f32_16x16x32_bf16(aw0h, bx, acc[0][ft], 0, 0, 0);
            acc[0][ft] = __builtin_amdgcn_mfma_f32_16x16x32_bf16(aw0l, bx, acc[0][ft], 0, 0, 0);
            acc[1][ft] = __builtin_amdgcn_mfma_f32_16x16x32_bf16(aw1h, bx, acc[1][ft], 0, 0, 0);
            acc[1][ft] = __builtin_amdgcn_mfma_f32_16x16x32_bf16(aw1l, bx, acc[1][ft], 0, 0, 0);
        }
    }

    int h = wave;
    float ap = alpha[h];
    float sum = 0.f, ss = 0.f;
#pragma unroll
    for (int a = 0; a < 2; a++) {
        int er0 = wave * 32 + a * 16 + gq * 4;
#pragma unroll
        for (int r = 0; r < 4; r++) {
            float bb = bias[er0 + r];
#pragma unroll
            for (int ft = 0; ft < 5; ft++) {
                float v = acc[a][ft][r] + bb;
                v = (v >= 0.f) ? v : ap * v;
                acc[a][ft][r] = v;
                int f = ft * 16 + n;
                if (f < F_) { sum += v; ss += v * v; }
            }
        }
    }
    sum = wred_sum(sum); ss = wred_sum(ss);
    float mu = sum * (1.f / 2080.f);
    float var = ss * (1.f / 2080.f) - mu * mu;
    float rs = rsqrtf(var + EPS);

    size_t obase = (size_t)((h * B_ + b) * TC_ + t) * DV;
#pragma unroll
    for (int a = 0; a < 2; a++) {
#pragma unroll
        for (int r = 0; r < 4; r++) {
            int er = wave * 32 + a * 16 + gq * 4 + r;
            int drow = er & 31;
#pragma unroll
            for (int ft = 0; ft < 5; ft++) {
                int f = ft * 16 + n;
                if (f < F_) {
                    out[obase + drow * F_ + f] =
                        f2bf((acc[a][ft][r] - mu) * rs * g[er * F_ + f] + bet[er * F_ + f]);
                }
            }
        }
    }
}

// ------- 3b. transpose V -> fragment-ordered Vt[hb][p][c][eh][lane][8] ----
// block per (hb, p): stages Vf rows [s 0..415]x[e p*32..p*32+31] in LDS,
// emits MFMA-A-fragment order so attn's PV load is one contiguous 1KB/wave.
__global__ __launch_bounds__(256)
void transpose_v_kernel(const u16* __restrict__ Vf, u16* __restrict__ Vt) {
    __shared__ u16 tile[32 * 424];          // [e_local][s], stride 424 (16B-aligned rows)
    int p  = blockIdx.x % 65;
    int hb = blockIdx.x / 65;
    const u16* src = Vf + (size_t)hb * TC_ * DV + p * 32;
    u16* dst = Vt + ((size_t)hb * 65 + p) * VTP;
    int tid = threadIdx.x;
    for (int i = tid; i < 416 * 32; i += 256) {
        int e = i & 31, s = i >> 5;         // e-fast: coalesced 64B per 32 lanes
        tile[e * 424 + s] = (s < TC_) ? src[(size_t)s * DV + e] : (u16)0;
    }
    __syncthreads();
    for (int k = tid; k < 1664; k += 256) { // 1664 chunks of 8 u16 (16B)
        int c = k >> 7, r = k & 127;
        int eh = r >> 6, l = r & 63;
        int nn = l & 15, gg = l >> 4;
        uint4 val = *(const uint4*)(&tile[(eh * 16 + nn) * 424 + c * 32 + gg * 8]);
        *(uint4*)(&dst[(size_t)k * 8]) = val;   // fully coalesced
    }
}

// ---------------- 4. MFMA attention: block per (h,b, 32 q rows) -----------
// Two 16-row QK^T passes share one LDS buffer (then reused for P 32x424).
// PV reads fragment-ordered Vt (contiguous 1KB/wave) and shares each V
// fragment across both q-subtiles -> V L2-traffic halved vs 16-row blocks.
__global__ __launch_bounds__(256, 3)
void attn_kernel(const u16* __restrict__ Qf, const u16* __restrict__ Kf,
                 const u16* __restrict__ Vt, float* __restrict__ out) {
    __shared__ u16 shbuf[32 * 424];         // Q pass: 16x552 (8832 u16); P: 32x424
    __shared__ float redmax[32 * 4];
    __shared__ float redsum[32 * 4];

    int tile = blockIdx.x & 31;
    int hb   = blockIdx.x >> 5;             // h*4 + b
    int h = hb >> 2, b = hb & 3;
    int tid = threadIdx.x;
    int wave = tid >> 6, lane = tid & 63;
    int g = lane >> 4;
    int n = lane & 15;
    int tq0 = tile * 32;

    const u16* kslab = Kf + (size_t)hb * SP_ * DQKP;
    const u16* qbase = Qf + (size_t)hb * QROWS * DQK;

    f32x4 acc[2][7];
#pragma unroll
    for (int qt = 0; qt < 2; qt++)
#pragma unroll
        for (int i = 0; i < 7; i++) acc[qt][i] = (f32x4){0.f, 0.f, 0.f, 0.f};

    // ---- QK^T: two 16-row passes ----
#pragma unroll
    for (int qt = 0; qt < 2; qt++) {
        for (int i = tid; i < 16 * 69; i += 256) {
            int q = i / 69, cb = i % 69;
            int qg = tq0 + qt * 16 + q;
            uint4 val = make_uint4(0, 0, 0, 0);
            if (qg < QROWS && cb < 65)
                val = *(const uint4*)(qbase + (size_t)qg * DQK + cb * 8);
            *(uint4*)(&shbuf[q * 552 + cb * 8]) = val;
        }
        __syncthreads();
        for (int c = 0; c < 17; c++) {
            bfrag aq = *(const bfrag*)(&shbuf[n * 552 + c * 32 + g * 8]);
#pragma unroll
            for (int i = 0; i < 7; i++) {
                int tau = wave + 4 * i;
                if (tau < 26) {
                    bfrag bk = *(const bfrag*)(kslab + (size_t)(tau * 16 + n) * DQKP + c * 32 + g * 8);
                    acc[qt][i] = __builtin_amdgcn_mfma_f32_16x16x32_bf16(aq, bk, acc[qt][i], 0, 0, 0);
                }
            }
        }
        __syncthreads();                    // qlds reads done before restage / P write
    }

    // ---- softmax over s; rows q = qt*16 + g*4 + r ----
    const float scale = 0.043852900965f;    // 1/sqrt(520)
    float m4[2][4], s4[2][4];
#pragma unroll
    for (int qt = 0; qt < 2; qt++) {
#pragma unroll
        for (int r = 0; r < 4; r++) {
            float mx = -1e30f;
#pragma unroll
            for (int i = 0; i < 7; i++) {
                int tau = wave + 4 * i;
                int s = tau * 16 + n;
                if (tau < 26 && s < TC_) mx = fmaxf(mx, acc[qt][i][r] * scale);
            }
            mx = fmaxf(mx, __shfl_xor(mx, 1, 64));
            mx = fmaxf(mx, __shfl_xor(mx, 2, 64));
            mx = fmaxf(mx, __shfl_xor(mx, 4, 64));
            mx = fmaxf(mx, __shfl_xor(mx, 8, 64));
            m4[qt][r] = mx;
        }
    }
    if (n == 0) {
#pragma unroll
        for (int qt = 0; qt < 2; qt++)
#pragma unroll
            for (int r = 0; r < 4; r++)
                redmax[(qt * 16 + g * 4 + r) * 4 + wave] = m4[qt][r];
    }
    __syncthreads();
#pragma unroll
    for (int qt = 0; qt < 2; qt++)
#pragma unroll
        for (int r = 0; r < 4; r++) {
            int q = qt * 16 + g * 4 + r;
            m4[qt][r] = fmaxf(fmaxf(redmax[q * 4 + 0], redmax[q * 4 + 1]),
                              fmaxf(redmax[q * 4 + 2], redmax[q * 4 + 3]));
            s4[qt][r] = 0.f;
        }
#pragma unroll
    for (int i = 0; i < 7; i++) {
        int tau = wave + 4 * i;
        if (tau < 26) {
            int s = tau * 16 + n;
#pragma unroll
            for (int qt = 0; qt < 2; qt++)
#pragma unroll
                for (int r = 0; r < 4; r++) {
                    float e = (s < TC_) ? __expf(acc[qt][i][r] * scale - m4[qt][r]) : 0.f;
                    acc[qt][i][r] = e;
                    s4[qt][r] += e;
                }
        }
    }
#pragma unroll
    for (int qt = 0; qt < 2; qt++)
#pragma unroll
        for (int r = 0; r < 4; r++) {
            float sm = s4[qt][r];
            sm += __shfl_xor(sm, 1, 64);
            sm += __shfl_xor(sm, 2, 64);
            sm += __shfl_xor(sm, 4, 64);
            sm += __shfl_xor(sm, 8, 64);
            s4[qt][r] = sm;
        }
    if (n == 0) {
#pragma unroll
        for (int qt = 0; qt < 2; qt++)
#pragma unroll
            for (int r = 0; r < 4; r++)
                redsum[(qt * 16 + g * 4 + r) * 4 + wave] = s4[qt][r];
    }
    __syncthreads();
#pragma unroll
    for (int qt = 0; qt < 2; qt++)
#pragma unroll
        for (int r = 0; r < 4; r++) {
            int q = qt * 16 + g * 4 + r;
            float tot = redsum[q * 4 + 0] + redsum[q * 4 + 1] +
                        redsum[q * 4 + 2] + redsum[q * 4 + 3];
            s4[qt][r] = 1.0f / tot;
        }
    // ---- write P (bf16) into shbuf: rows 0..31, cols s (416, zero-padded) --
#pragma unroll
    for (int i = 0; i < 7; i++) {
        int tau = wave + 4 * i;
        if (tau < 26) {
            int s = tau * 16 + n;
#pragma unroll
            for (int qt = 0; qt < 2; qt++)
#pragma unroll
                for (int r = 0; r < 4; r++)
                    shbuf[(qt * 16 + g * 4 + r) * 424 + s] = f2bf(acc[qt][i][r] * s4[qt][r]);
        }
    }
    __syncthreads();

    // ---- PV: O^T = V^T . P^T ; bp preloaded for both q-subtiles ----
    bfrag bp[2][13];
#pragma unroll
    for (int qt = 0; qt < 2; qt++)
#pragma unroll
        for (int c = 0; c < 13; c++)
            bp[qt][c] = *(const bfrag*)(&shbuf[(qt * 16 + n) * 424 + c * 32 + g * 8]);

    const u16* vslab = Vt + (size_t)hb * 65 * VTP;
    for (int j = 0; j < 17; j++) {
        int p = wave + 4 * j;               // 32-e-row group (wave-uniform)
        if (p >= 65) break;
        const u16* vb = vslab + (size_t)p * VTP + lane * 8;
        f32x4 a00 = (f32x4){0.f,0.f,0.f,0.f}, a01 = (f32x4){0.f,0.f,0.f,0.f};
        f32x4 a10 = (f32x4){0.f,0.f,0.f,0.f}, a11 = (f32x4){0.f,0.f,0.f,0.f};
#pragma unroll
        for (int c = 0; c < 13; c++) {
            bfrag v0 = *(const bfrag*)(vb + c * 1024);        // eh=0: contiguous 1KB/wave
            bfrag v1 = *(const bfrag*)(vb + c * 1024 + 512);  // eh=1
            a00 = __builtin_amdgcn_mfma_f32_16x16x32_bf16(v0, bp[0][c], a00, 0, 0, 0);
            a01 = __builtin_amdgcn_mfma_f32_16x16x32_bf16(v0, bp[1][c], a01, 0, 0, 0);
            a10 = __builtin_amdgcn_mfma_f32_16x16x32_bf16(v1, bp[0][c], a10, 0, 0, 0);
            a11 = __builtin_amdgcn_mfma_f32_16x16x32_bf16(v1, bp[1][c], a11, 0, 0, 0);
        }
        int e0 = p * 32;
#pragma unroll
        for (int qt = 0; qt < 2; qt++) {
            int t = tq0 + qt * 16 + n;
            if (t < T_) {
#pragma unroll
                for (int r = 0; r < 4; r++) {
                    int e = e0 + g * 4 + r;
                    int dh = e / F_, f = e - dh * F_;
                    float v0w = qt ? a01[r] : a00[r];
                    out[((size_t)(b * C_ + h * DH_ + dh) * T_ + t) * F_ + f] = v0w;
                    int e2 = e0 + 16 + g * 4 + r;
                    int dh2 = e2 / F_, f2 = e2 - dh2 * F_;
                    float v1w = qt ? a11[r] : a10[r];
                    out[((size_t)(b * C_ + h * DH_ + dh2) * T_ + t) * F_ + f2] = v1w;
                }
            }
        }
    }
}

// ---------------- 4b. convert Wp to split bf16 (hi, lo) -------------------
__global__ __launch_bounds__(256)
void wconv_kernel(const float* __restrict__ W, u16* __restrict__ Wbf) {
    int i = blockIdx.x * 256 + threadIdx.x;
    if (i < C_ * C_) {
        float v = W[i];
        u16 hi = f2bf(v);
        Wbf[i] = hi;
        Wbf[C_ * C_ + i] = f2bf(v - bf2f(hi));
    }
}

// ---------------- 5. projection via MFMA (split W) ------------------------
__global__ __launch_bounds__(256, 4)
void proj_mfma_kernel(float* __restrict__ io, const u16* __restrict__ Wbf,
                      const float* __restrict__ bpr, const float* __restrict__ apr,
                      const float* __restrict__ gpr, const float* __restrict__ betpr) {
    __shared__ u16 xt[80 * 136];
    __shared__ float wsum[4], wss[4];
    int b = blockIdx.x / T_, t = blockIdx.x % T_;
    int tid = threadIdx.x;
    size_t xbase = (size_t)(b * C_) * T_ * F_ + (size_t)t * F_;

    for (int i = tid; i < C_ * F_; i += 256) {
        int c = i / F_, f = i % F_;
        xt[f * 136 + c] = f2bf(io[xbase + (size_t)c * T_ * F_ + f]);
    }
    for (int i = tid; i < 15 * 128; i += 256) {
        int f = 65 + i / 128, c = i % 128;
        xt[f * 136 + c] = 0;
    }
    __syncthreads();

    int wave = tid >> 6, lane = tid & 63, g = lane >> 4, n = lane & 15;
    const u16* Wlo = Wbf + C_ * C_;
    f32x4 acc[2][5];
#pragma unroll
    for (int a = 0; a < 2; a++)
#pragma unroll
        for (int ft = 0; ft < 5; ft++) acc[a][ft] = (f32x4){0.f, 0.f, 0.f, 0.f};

    for (int c32 = 0; c32 < 4; c32++) {
        bfrag aw0h = *(const bfrag*)(Wbf + (size_t)(wave * 32 + n) * C_ + c32 * 32 + g * 8);
        bfrag aw0l = *(const bfrag*)(Wlo + (size_t)(wave * 32 + n) * C_ + c32 * 32 + g * 8);
        bfrag aw1h = *(const bfrag*)(Wbf + (size_t)(wave * 32 + 16 + n) * C_ + c32 * 32 + g * 8);
        bfrag aw1l = *(const bfrag*)(Wlo + (size_t)(wave * 32 + 16 + n) * C_ + c32 * 32 + g * 8);
#pragma unroll
        for (int ft = 0; ft < 5; ft++) {
            bfrag bx = *(const bfrag*)(&xt[(ft * 16 + n) * 136 + c32 * 32 + g * 8]);
            acc[0][ft] = __builtin_amdgcn_mfma_f32_16x16x32_bf16(aw0h, bx, acc[0][ft], 0, 0, 0);
            acc[0][ft] = __builtin_amdgcn_mfma_f32_16x16x32_bf16(aw0l, bx, acc[0][ft], 0, 0, 0);
            acc[1][ft] = __builtin_amdgcn_mfma_f32_16x16x32_bf16(aw1h, bx, acc[1][ft], 0, 0, 0);
            acc[1][ft] = __builtin_amdgcn_mfma_f32_16x16x32_bf16(aw1l, bx, acc[1][ft], 0, 0, 0);
        }
    }

    float a_p = apr[0];
    float sum = 0.f, ss = 0.f;
#pragma unroll
    for (int a = 0; a < 2; a++) {
        int e0 = wave * 32 + a * 16 + g * 4;
#pragma unroll
        for (int r = 0; r < 4; r++) {
            float bb = bpr[e0 + r];
#pragma unroll
            for (int ft = 0; ft < 5; ft++) {
                float v = acc[a][ft][r] + bb;
                v = (v >= 0.f) ? v : a_p * v;
                acc[a][ft][r] = v;
                int f = ft * 16 + n;
                if (f < F_) { sum += v; ss += v * v; }
            }
        }
    }
    sum = wred_sum(sum); ss = wred_sum(ss);
    if (lane == 0) { wsum[wave] = sum; wss[wave] = ss; }
    __syncthreads();
    float tsum = wsum[0] + wsum[1] + wsum[2] + wsum[3];
    float tss  = wss[0] + wss[1] + wss[2] + wss[3];
    float mu = tsum * (1.f / 8320.f);
    float var = tss * (1.f / 8320.f) - mu * mu;
    float rs = rsqrtf(var + EPS);

#pragma unroll
    for (int a = 0; a < 2; a++) {
#pragma unroll
        for (int r = 0; r < 4; r++) {
            int e = wave * 32 + a * 16 + g * 4 + r;
#pragma unroll
            for (int ft = 0; ft < 5; ft++) {
                int f = ft * 16 + n;
                if (f < F_) {
                    io[((size_t)(b * C_ + e) * T_ + t) * F_ + f] =
                        (acc[a][ft][r] - mu) * rs * gpr[e * F_ + f] + betpr[e * F_ + f];
                }
            }
        }
    }
}

extern "C" void kernel_launch(void* const* d_in, const int* in_sizes, int n_in,
                              void* d_out, int out_size, void* d_ws, size_t ws_size,
                              hipStream_t stream) {
    const float* batch = (const float*)d_in[0];
    const float* pos   = (const float*)d_in[1];
    const float* neg   = (const float*)d_in[2];
    const float* WQ   = (const float*)d_in[3];
    const float* bQ   = (const float*)d_in[4];
    const float* aQ   = (const float*)d_in[5];
    const float* gQ   = (const float*)d_in[6];
    const float* betQ = (const float*)d_in[7];
    const float* WK   = (const float*)d_in[8];
    const float* bK   = (const float*)d_in[9];
    const float* aK   = (const float*)d_in[10];
    const float* gK   = (const float*)d_in[11];
    const float* betK = (const float*)d_in[12];
    const float* WV   = (const float*)d_in[13];
    const float* bV   = (const float*)d_in[14];
    const float* aV   = (const float*)d_in[15];
    const float* gV   = (const float*)d_in[16];
    const float* betV = (const float*)d_in[17];
    const float* Wp   = (const float*)d_in[18];
    const float* bp   = (const float*)d_in[19];
    const float* ap   = (const float*)d_in[20];
    const float* gp   = (const float*)d_in[21];
    const float* betp = (const float*)d_in[22];

    char* ws = (char*)d_ws;
    // layout (cond aliases Vt; cond is dead before transpose writes Vt):
    //   Vt   [0, 27,688,960)          16*65*13312*2 (fragment-ordered)
    //     cond  [0, 26,490,880)       aliases Vt head (dead before transpose)
    //     Wqkv  [26,490,880, 26,589,184)  split bf16 W, dead before transpose
    //   Qf   [27,688,960, 44,462,080) 16*1008*520*2
    //   Kf   [44,462,080, 51,703,808) 16*416*544*2
    //   Vf   [51,703,808, 78,194,688) 16*398*2080*2
    //   Wpbf aliases Vf start (Vf dead after transpose_v); hi+lo = 65,536 B
    u16* Vt   = (u16*)(ws);
    u16* cond = (u16*)(ws);
    u16* Wqkv = (u16*)(ws + 26490880);
    u16* Qf   = (u16*)(ws + 27688960);
    u16* Kf   = (u16*)(ws + 44462080);
    u16* Vf   = (u16*)(ws + 51703808);
    u16* Wpbf = (u16*)(ws + 51703808);
    u16* WQbf = Wqkv;            // hi at 0, lo at +4096
    u16* WKbf = Wqkv + 8192;     // hi, lo at +4096
    u16* WVbf = Wqkv + 16384;    // hi, lo at +16384
    float* o  = (float*)d_out;

    wconv3_kernel<<<96, 256, 0, stream>>>(WQ, WK, WV, Wqkv);
    const int NPOOL = B_ * C_ * TC_ * F_;
    pool_kernel<<<(NPOOL + 255) / 256, 256, 0, stream>>>(pos, neg, cond);
    const int KF16 = (16 * SP_ * DQKP * 2) / 16;
    zerofill_kernel<<<(KF16 + 255) / 256, 256, 0, stream>>>((uint4*)Kf, KF16);
    qk_mfma_kernel<float, true><<<B_ * T_,  256, 0, stream>>>(batch, T_,  QROWS, DQK,  WQbf, bQ, aQ, gQ, betQ, Qf);
    qk_mfma_kernel<u16, false> <<<B_ * TC_, 256, 0, stream>>>(cond,  TC_, SP_,   DQKP, WKbf, bK, aK, gK, betK, Kf);
    v_mfma_kernel<<<B_ * TC_, 256, 0, stream>>>(cond, WVbf, bV, aV, gV, betV, Vf);
    transpose_v_kernel<<<16 * 65, 256, 0, stream>>>(Vf, Vt);
    wconv_kernel<<<(C_ * C_ + 255) / 256, 256, 0, stream>>>(Wp, Wpbf);
    attn_kernel<<<16 * 32, 256, 0, stream>>>(Qf, Kf, Vt, o);
    proj_mfma_kernel<<<B_ * T_, 256, 0, stream>>>(o, Wpbf, bp, ap, gp, betp);
}